// Round 9
// baseline (234.433 us; speedup 1.0000x reference)
//
#include <hip/hip_runtime.h>

#define B_SZ   2
#define NH     16
#define S_LEN  2048
#define DK     64
#define EMB    1024
#define M_TOT  (B_SZ * S_LEN)   // 4096
#define KT     64

typedef float          f32x4  __attribute__((ext_vector_type(4)));
typedef float          f32x16 __attribute__((ext_vector_type(16)));
typedef unsigned int   u32x4  __attribute__((ext_vector_type(4)));
typedef unsigned short u16x8  __attribute__((ext_vector_type(8)));
typedef unsigned short u16x4  __attribute__((ext_vector_type(4)));
typedef __bf16         bf16x8 __attribute__((ext_vector_type(8)));

static __device__ __forceinline__ f32x4 mfma16(u16x8 a, u16x8 b, f32x4 c) {
    return __builtin_amdgcn_mfma_f32_16x16x32_bf16(
        __builtin_bit_cast(bf16x8, a), __builtin_bit_cast(bf16x8, b), c, 0, 0, 0);
}
static __device__ __forceinline__ f32x16 mfma32(u16x8 a, u16x8 b, f32x16 c) {
    return __builtin_amdgcn_mfma_f32_32x32x16_bf16(
        __builtin_bit_cast(bf16x8, a), __builtin_bit_cast(bf16x8, b), c, 0, 0, 0);
}

// round-to-nearest-even fp32 -> bf16 (finite inputs)
static __device__ __forceinline__ unsigned short f2bf(float f) {
    unsigned int u = __builtin_bit_cast(unsigned int, f);
    u = (u + 0x7FFFu + ((u >> 16) & 1u)) >> 16;
    return (unsigned short)u;
}

// hardware 2^x
static __device__ __forceinline__ float exp2_hw(float x) {
    float r; asm("v_exp_f32 %0, %1" : "=v"(r) : "v"(x)); return r;
}

// async global -> LDS, 16B per lane; LDS dest = uniform base + lane*16
#define GLDS16(g, l)  __builtin_amdgcn_global_load_lds(                      \
    (const void __attribute__((address_space(1)))*)(g),                      \
    (void __attribute__((address_space(3)))*)(l), 16, 0, 0)

// ---------------------------------------------------------------- convert
__global__ __launch_bounds__(256) void cvt_kernel(
    const float* __restrict__ x,  const float* __restrict__ wq,
    const float* __restrict__ wk, const float* __restrict__ wv,
    unsigned short* __restrict__ xb,  unsigned short* __restrict__ wqb,
    unsigned short* __restrict__ wkb, unsigned short* __restrict__ wvb)
{
    long gid = (long)blockIdx.x * 256 + threadIdx.x;
    long e = gid * 4;
    const float* src; unsigned short* dst; long off;
    if      (e < 4194304L) { src = x;  dst = xb;  off = e; }
    else if (e < 5242880L) { src = wq; dst = wqb; off = e - 4194304L; }
    else if (e < 6291456L) { src = wk; dst = wkb; off = e - 5242880L; }
    else                   { src = wv; dst = wvb; off = e - 6291456L; }
    f32x4 v = *(const f32x4*)(src + off);
    u16x4 u;
    u[0] = f2bf(v[0]); u[1] = f2bf(v[1]); u[2] = f2bf(v[2]); u[3] = f2bf(v[3]);
    *(u16x4*)(dst + off) = u;
}

// ---------------------------------------------------------------- QKV GEMM
// m97 template + both-sides XOR swizzle (rule #21):
//   LDS linear [row][64]; global SOURCE pre-swizzled so LDS(row, slot) holds
//   global slot (slot ^ (row&7)); fragment read XORs slot with (l15&7).
#define BM 128
#define BN 128
#define BK 64

__global__ __launch_bounds__(256) void qkv_gemm(
    const unsigned short* __restrict__ xb,
    const unsigned short* __restrict__ wb,
    const float* __restrict__ bq, const float* __restrict__ bk,
    const float* __restrict__ bv,
    unsigned short* __restrict__ qkv)
{
    const int tid  = threadIdx.x;
    const int lane = tid & 63;
    const int wid  = tid >> 6;
    const int wm   = wid >> 1, wn = wid & 1;
    const int n0   = blockIdx.x * BN;
    const int m0   = blockIdx.y * BM;
    const int mat  = blockIdx.z;

    const unsigned short* wmat = wb + (size_t)mat * (1024 * 1024);
    const float* bias = (mat == 0) ? bq : ((mat == 1) ? bk : bv);
    unsigned short* dst = qkv + (size_t)mat * ((size_t)M_TOT * EMB);

    __shared__ __align__(16) unsigned short Al[BM * 64];
    __shared__ __align__(16) unsigned short Bl[BN * 64];

    f32x4 acc[4][4];
#pragma unroll
    for (int i = 0; i < 4; ++i)
#pragma unroll
        for (int j = 0; j < 4; ++j)
            acc[i][j] = (f32x4){0.f, 0.f, 0.f, 0.f};

    const int wrow = wid * 32;                    // wave's staging row block
    const int lrow = lane >> 3;                   // row within 8-row stripe
    const int lcol = ((lane & 7) ^ lrow) * 8;     // PRE-SWIZZLED source slot
    const int l15  = lane & 15;
    // fragment-read slots (slot = (kk*4 + lane>>4) ^ (row&7), row&7 = l15&7)
    const int sl0 = (((lane >> 4))     ^ (l15 & 7)) * 8;   // kk = 0
    const int sl1 = ((4 + (lane >> 4)) ^ (l15 & 7)) * 8;   // kk = 1

    for (int k0 = 0; k0 < EMB; k0 += BK) {
        const unsigned short* ga = xb   + (size_t)(m0 + wrow + lrow) * EMB + k0 + lcol;
        const unsigned short* gb = wmat + (size_t)(n0 + wrow + lrow) * EMB + k0 + lcol;
#pragma unroll
        for (int j = 0; j < 4; ++j) {
            GLDS16(ga + (size_t)j * 8 * EMB, &Al[(wrow + j * 8) * 64]);
            GLDS16(gb + (size_t)j * 8 * EMB, &Bl[(wrow + j * 8) * 64]);
        }
        __syncthreads();     // drains vmcnt -> staged tile visible

#pragma unroll
        for (int kk = 0; kk < 2; ++kk) {
            const int sl = kk ? sl1 : sl0;
            u16x8 a[4], b[4];
#pragma unroll
            for (int i = 0; i < 4; ++i)
                a[i] = *(const u16x8*)&Al[(wm * 64 + i * 16 + l15) * 64 + sl];
#pragma unroll
            for (int j = 0; j < 4; ++j)
                b[j] = *(const u16x8*)&Bl[(wn * 64 + j * 16 + l15) * 64 + sl];
#pragma unroll
            for (int i = 0; i < 4; ++i)
#pragma unroll
                for (int j = 0; j < 4; ++j)
                    acc[i][j] = mfma16(a[i], b[j], acc[i][j]);
        }
        __syncthreads();
    }

#pragma unroll
    for (int j = 0; j < 4; ++j) {
        int n = n0 + wn * 64 + j * 16 + l15;
        float bvv = bias[n];
        int h = n >> 6, d = n & 63;
#pragma unroll
        for (int i = 0; i < 4; ++i) {
#pragma unroll
            for (int r = 0; r < 4; ++r) {
                int m = m0 + wm * 64 + i * 16 + ((lane >> 4) << 2) + r;
                int bb = m >> 11, s = m & 2047;
                dst[((size_t)((bb * NH + h) * S_LEN + s)) * DK + d] =
                    f2bf(acc[i][j][r] + bvv);
            }
        }
    }
}

// ---------------------------------------------------------------- attention
// 16 waves (1024 thr) = 4 K-interleave groups x 4 q-waves.  Each block
// serially processes q-tiles yp and 15-yp -> every block has IDENTICAL total
// work (grid 256 = 1 block/CU, sustained 16 waves/CU, zero drain imbalance).
// Swapped QK^T (32x32 MFMA), in-register exp2 softmax with defer-max,
// row-sum via mfma32(ones, P), cvt_pk+permlane32 P->B, 4-way LSE merge.
__global__ __launch_bounds__(1024, 4) void attn_kernel(
    const unsigned short* __restrict__ Q,
    const unsigned short* __restrict__ K,
    const unsigned short* __restrict__ V,
    const int* __restrict__ mskp,
    float* __restrict__ out)
{
    const int tid = threadIdx.x, lane = tid & 63, wid = tid >> 6;
    const int grp = wid >> 2, qw = wid & 3;
    const int l31 = lane & 31, H = lane >> 5;
    const int bh = blockIdx.x;
    const int h  = bh & 15, b = bh >> 4;
    const int yp = blockIdx.y;             // 0..7: q-tile pair (yp, 15-yp)
    const size_t hoff = ((size_t)(b * NH + h)) * S_LEN * DK;
    const unsigned short* Qh = Q + hoff;
    const unsigned short* Kh = K + hoff;
    const unsigned short* Vh = V + hoff;
    const int msk = *mskp;

    __shared__ __align__(16) unsigned short Kl[4][64 * 64];   // 32 KB
    __shared__ __align__(16) unsigned short Vt[4][64 * 64];   // 32 KB
    __shared__ float MLbuf[3 * 512];                          // 6 KB
    unsigned short* Kg = Kl[grp];
    unsigned short* Vg = Vt[grp];

    u16x8 ones1;
#pragma unroll
    for (int i = 0; i < 8; ++i) ones1[i] = 0x3F80;   // bf16 1.0

    const int gt  = tid & 255;              // thread within group
    const int sr0 = gt >> 3, sc8 = gt & 7, sr1 = sr0 + 32;
    const int kwo0 = sr0 * 64 + ((sc8 ^ (sr0 & 7)) << 3);
    const int kwo1 = sr1 * 64 + ((sc8 ^ (sr1 & 7)) << 3);
    const int vwo0 = (((sr0 >> 3) ^ sc8) << 3) + (sr0 & 7);
    const int vwo1 = (((sr1 >> 3) ^ sc8) << 3) + (sr1 & 7);

    const int dsw0 = l31 >> 3, dsw1 = 4 + (l31 >> 3);
    const int rsw  = l31 & 7;
    const float SC2 = 0.125f * 1.4426950408889634f;   // fold log2(e)
    const int idx  = qw * 64 + lane;                  // merge row index

    for (int seg = 0; seg < 2; ++seg) {
        const int qt = seg ? (15 - yp) : yp;
        const int q0 = qt * 128;
        const int ntiles = msk ? (2 * qt + 2) : (S_LEN / KT);
        const int niter  = (ntiles + 3) >> 2;
        const int qrow = q0 + qw * 32 + l31;
        const int qmin = q0 + qw * 32;

        u16x8 qf[4];
#pragma unroll
        for (int ks = 0; ks < 4; ++ks)
            qf[ks] = *(const u16x8*)(Qh + (size_t)qrow * DK + ks * 16 + H * 8);

        f32x16 o0, o1, lacc;
#pragma unroll
        for (int i = 0; i < 16; ++i) { o0[i] = 0.f; o1[i] = 0.f; lacc[i] = 0.f; }
        float mx = -1e30f;

        // prologue: load tile 'grp' to regs (rows <=255, always in-bounds)
        u16x8 kr[2], vr[2];
        {
            const unsigned short* K0 = Kh + (size_t)grp * KT * DK;
            const unsigned short* V0 = Vh + (size_t)grp * KT * DK;
            kr[0] = *(const u16x8*)(K0 + (size_t)sr0 * DK + sc8 * 8);
            vr[0] = *(const u16x8*)(V0 + (size_t)sr0 * DK + sc8 * 8);
            kr[1] = *(const u16x8*)(K0 + (size_t)sr1 * DK + sc8 * 8);
            vr[1] = *(const u16x8*)(V0 + (size_t)sr1 * DK + sc8 * 8);
        }
        __syncthreads();   // seg=1: previous merge's LDS reads all done
        *(u16x8*)&Kg[kwo0] = kr[0];
        *(u16x8*)&Kg[kwo1] = kr[1];
#pragma unroll
        for (int e = 0; e < 8; ++e) {
            Vg[(sc8 * 8 + e) * 64 + vwo0] = vr[0][e];
            Vg[(sc8 * 8 + e) * 64 + vwo1] = vr[1][e];
        }
        if (grp + 4 < ntiles) {
            const unsigned short* Kn = Kh + (size_t)(grp + 4) * KT * DK;
            const unsigned short* Vn = Vh + (size_t)(grp + 4) * KT * DK;
            kr[0] = *(const u16x8*)(Kn + (size_t)sr0 * DK + sc8 * 8);
            vr[0] = *(const u16x8*)(Vn + (size_t)sr0 * DK + sc8 * 8);
            kr[1] = *(const u16x8*)(Kn + (size_t)sr1 * DK + sc8 * 8);
            vr[1] = *(const u16x8*)(Vn + (size_t)sr1 * DK + sc8 * 8);
        }
        __syncthreads();   // staged tiles visible

        for (int it = 0; it < niter; ++it) {
            const int kt = 4 * it + grp;

            if (kt < ntiles && !(msk && kt * KT > qmin + 31)) {
                // ---- S^T = K Q^T ----
                f32x16 st0, st1;
#pragma unroll
                for (int i = 0; i < 16; ++i) { st0[i] = 0.f; st1[i] = 0.f; }
                __builtin_amdgcn_s_setprio(1);
#pragma unroll
                for (int ks = 0; ks < 4; ++ks) {
                    const int g = (((ks << 1) + H) ^ rsw) << 3;
                    u16x8 kf0 = *(const u16x8*)&Kg[l31 * 64 + g];
                    u16x8 kf1 = *(const u16x8*)&Kg[(32 + l31) * 64 + g];
                    st0 = mfma32(kf0, qf[ks], st0);
                    st1 = mfma32(kf1, qf[ks], st1);
                }
                __builtin_amdgcn_s_setprio(0);

                // scale (exp2 domain) + causal mask
                st0 *= SC2;
                st1 *= SC2;
                float p[32];
#pragma unroll
                for (int r = 0; r < 16; ++r) { p[r] = st0[r]; p[16 + r] = st1[r]; }
                const bool needmask = msk && (kt * KT + 63 > qrow);
                if (needmask) {
#pragma unroll
                    for (int r = 0; r < 16; ++r) {
                        const int krow = (r & 3) + 8 * (r >> 2) + 4 * H;
                        if (kt * KT + krow > qrow)      p[r]      = -1e30f;
                        if (kt * KT + 32 + krow > qrow) p[16 + r] = -1e30f;
                    }
                }

                // tile max: register tree + one shfl(32); defer-max rescale
                float t8[8];
#pragma unroll
                for (int i = 0; i < 8; ++i)
                    t8[i] = fmaxf(fmaxf(p[i], p[i + 8]), fmaxf(p[i + 16], p[i + 24]));
#pragma unroll
                for (int i = 0; i < 4; ++i) t8[i] = fmaxf(t8[i], t8[i + 4]);
                float mt = fmaxf(fmaxf(t8[0], t8[1]), fmaxf(t8[2], t8[3]));
                mt = fmaxf(mt, __shfl_xor(mt, 32, 64));

                if (!__all(mt <= mx + 11.54f)) {   // 8 nats in log2 domain
                    const float mn = fmaxf(mx, mt);
                    const float al = exp2_hw(mx - mn);
                    mx = mn;
                    o0 *= al; o1 *= al;
                    lacc[0] *= al;
                }

#pragma unroll
                for (int r = 0; r < 32; ++r) p[r] = exp2_hw(p[r] - mx);

                // P^T -> bf16 B-fragments; PV + row-sum via ones-MFMA
                __builtin_amdgcn_s_setprio(1);
#pragma unroll
                for (int ks = 0; ks < 4; ++ks) {
                    const int bb = ks * 8;
                    unsigned int wa, wb2, wc, wd;
                    asm("v_cvt_pk_bf16_f32 %0, %1, %2" : "=v"(wa)  : "v"(p[bb + 0]), "v"(p[bb + 1]));
                    asm("v_cvt_pk_bf16_f32 %0, %1, %2" : "=v"(wb2) : "v"(p[bb + 2]), "v"(p[bb + 3]));
                    asm("v_cvt_pk_bf16_f32 %0, %1, %2" : "=v"(wc)  : "v"(p[bb + 4]), "v"(p[bb + 5]));
                    asm("v_cvt_pk_bf16_f32 %0, %1, %2" : "=v"(wd)  : "v"(p[bb + 6]), "v"(p[bb + 7]));
                    asm volatile("v_permlane32_swap_b32 %0, %1" : "+v"(wa),  "+v"(wc));
                    asm volatile("v_permlane32_swap_b32 %0, %1" : "+v"(wb2), "+v"(wd));
                    u32x4 wv; wv[0] = wa; wv[1] = wb2; wv[2] = wc; wv[3] = wd;
                    const u16x8 pb = __builtin_bit_cast(u16x8, wv);
                    const int kg = (ks << 1) + H;
                    u16x8 vf0 = *(const u16x8*)&Vg[l31 * 64        + ((kg ^ dsw0) << 3)];
                    u16x8 vf1 = *(const u16x8*)&Vg[(32 + l31) * 64 + ((kg ^ dsw1) << 3)];
                    o0 = mfma32(vf0, pb, o0);
                    o1 = mfma32(vf1, pb, o1);
                    lacc = mfma32(ones1, pb, lacc);
                }
                __builtin_amdgcn_s_setprio(0);
            }

            __syncthreads();   // all reads of this round's LDS done
            if (it + 1 < niter) {
                const int ktn = 4 * (it + 1) + grp;
                if (ktn < ntiles) {
                    *(u16x8*)&Kg[kwo0] = kr[0];
                    *(u16x8*)&Kg[kwo1] = kr[1];
#pragma unroll
                    for (int e = 0; e < 8; ++e) {
                        Vg[(sc8 * 8 + e) * 64 + vwo0] = vr[0][e];
                        Vg[(sc8 * 8 + e) * 64 + vwo1] = vr[1][e];
                    }
                }
                if (ktn + 4 < ntiles) {
                    const unsigned short* Kn = Kh + (size_t)(ktn + 4) * KT * DK;
                    const unsigned short* Vn = Vh + (size_t)(ktn + 4) * KT * DK;
                    kr[0] = *(const u16x8*)(Kn + (size_t)sr0 * DK + sc8 * 8);
                    vr[0] = *(const u16x8*)(Vn + (size_t)sr0 * DK + sc8 * 8);
                    kr[1] = *(const u16x8*)(Kn + (size_t)sr1 * DK + sc8 * 8);
                    vr[1] = *(const u16x8*)(Vn + (size_t)sr1 * DK + sc8 * 8);
                }
                __syncthreads();   // staged tiles visible
            }
        }

        // ---- 4-way LSE merge: (0<-1), (2<-3), then (0<-2) ----
        float lsum = lacc[0];
        __syncthreads();   // all compute done; K/V LDS free for reuse
        if (grp == 1 || grp == 3) {
            float* MO = ((grp == 1) ? (float*)Kl : (float*)Vt) + idx * 32;
#pragma unroll
            for (int i = 0; i < 16; ++i) {
                MO[(i + idx) & 31]      = o0[i];
                MO[(16 + i + idx) & 31] = o1[i];
            }
            float* ML = MLbuf + (grp == 1 ? 0 : 512);
            ML[idx * 2]     = mx;
            ML[idx * 2 + 1] = lsum;
        }
        __syncthreads();
        if (grp == 0 || grp == 2) {
            const float* MO = ((grp == 0) ? (float*)Kl : (float*)Vt) + idx * 32;
            const float* ML = MLbuf + (grp == 0 ? 0 : 512);
            const float m2 = ML[idx * 2], l2 = ML[idx * 2 + 1];
            const float mn = fmaxf(mx, m2);
            const float ea = exp2_hw(mx - mn);
            const float eb = exp2_hw(m2 - mn);
            mx = mn;
            lsum = lsum * ea + l2 * eb;
#pragma unroll
            for (int i = 0; i < 16; ++i) {
                o0[i] = o0[i] * ea + MO[(i + idx) & 31] * eb;
                o1[i] = o1[i] * ea + MO[(16 + i + idx) & 31] * eb;
            }
        }
        __syncthreads();   // round-A reads done before grp2 overwrites Kl
        if (grp == 2) {
            float* MO = (float*)Kl + idx * 32;
#pragma unroll
            for (int i = 0; i < 16; ++i) {
                MO[(i + idx) & 31]      = o0[i];
                MO[(16 + i + idx) & 31] = o1[i];
            }
            MLbuf[1024 + idx * 2]     = mx;
            MLbuf[1024 + idx * 2 + 1] = lsum;
        }
        __syncthreads();
        if (grp == 0) {
            const float* MO = (float*)Kl + idx * 32;
            const float m2 = MLbuf[1024 + idx * 2], l2 = MLbuf[1024 + idx * 2 + 1];
            const float mn = fmaxf(mx, m2);
            const float ea = exp2_hw(mx - mn);
            const float eb = exp2_hw(m2 - mn);
            const float inv = 1.f / (lsum * ea + l2 * eb);
            float* orow = out + ((size_t)(b * S_LEN) + qrow) * EMB + h * DK;
#pragma unroll
            for (int g = 0; g < 4; ++g) {
                f32x4 w0, w1;
#pragma unroll
                for (int i = 0; i < 4; ++i) {
                    w0[i] = (o0[4 * g + i] * ea + MO[(4 * g + i + idx) & 31] * eb) * inv;
                    w1[i] = (o1[4 * g + i] * ea + MO[(16 + 4 * g + i + idx) & 31] * eb) * inv;
                }
                *(f32x4*)&orow[8 * g + 4 * H]      = w0;
                *(f32x4*)&orow[32 + 8 * g + 4 * H] = w1;
            }
        }
    }
}

// ---------------------------------------------------------------- launch
extern "C" void kernel_launch(void* const* d_in, const int* in_sizes, int n_in,
                              void* d_out, int out_size, void* d_ws, size_t ws_size,
                              hipStream_t stream)
{
    const float* x  = (const float*)d_in[0];
    const float* wq = (const float*)d_in[1];
    const float* bq = (const float*)d_in[2];
    const float* wk = (const float*)d_in[3];
    const float* bk = (const float*)d_in[4];
    const float* wv = (const float*)d_in[5];
    const float* bv = (const float*)d_in[6];
    const int* msk  = (const int*)d_in[7];
    float* out = (float*)d_out;

    unsigned short* xb  = (unsigned short*)d_ws;
    unsigned short* wb  = xb + (size_t)M_TOT * EMB;
    unsigned short* qkv = wb + (size_t)3 * 1024 * 1024;

    cvt_kernel<<<7168, 256, 0, stream>>>(x, wq, wk, wv,
                                         xb, wb, wb + 1024 * 1024, wb + 2 * 1024 * 1024);
    qkv_gemm<<<dim3(8, 32, 3), 256, 0, stream>>>(xb, wb, bq, bk, bv, qkv);
    attn_kernel<<<dim3(32, 8, 1), 1024, 0, stream>>>(
        qkv, qkv + (size_t)M_TOT * EMB, qkv + (size_t)2 * M_TOT * EMB, msk, out);
}